// Round 8
// baseline (791.296 us; speedup 1.0000x reference)
//
#include <hip/hip_runtime.h>
#include <stdint.h>

typedef unsigned short ushort_t;

#define N_NODES 100000
#define N_EDGES 1600000
#define D 128
#define WS_NEED 34001056u

static __device__ __forceinline__ float bf2f(uint32_t u) {
    return __builtin_bit_cast(float, u << 16);
}
static __device__ __forceinline__ ushort_t f2bf(float f) {
    uint32_t u = __builtin_bit_cast(uint32_t, f);
    uint32_t r = u + 0x7fffu + ((u >> 16) & 1u);   // RNE
    return (ushort_t)(r >> 16);
}
// leaky_relu(0.2) -> clip(-2,2) -> exp.  Shared by fill & agg so the
// recomputed e in agg is bitwise identical to the one summed into sum_e.
static __device__ __forceinline__ float edge_e(float s) {
    float x = (s >= 0.0f) ? s : 0.2f * s;
    x = fminf(fmaxf(x, -2.0f), 2.0f);
    return __expf(x);
}

// ---------------- zero cnt + sum_e (ws is poisoned 0xAA every call) ----------
__global__ void zero_kernel(int* cnt, float* sum_e, int n) {
    int i = blockIdx.x * blockDim.x + threadIdx.x;
    if (i < n) { cnt[i] = 0; sum_e[i] = 0.0f; }
}

// ---------------- edge dtype: int64 (odd words all 0) vs int32 ---------------
__global__ void detect_kernel(const int* __restrict__ E, int* __restrict__ eflag) {
    __shared__ int s;
    int t = threadIdx.x;
    if (t == 0) s = 0;
    __syncthreads();
    int nz = 0;
#pragma unroll
    for (int j = 0; j < 8; j++) {
        if (E[(t + j * 256) * 2 + 1] != 0) nz = 1;
    }
    if (nz) atomicOr(&s, 1);
    __syncthreads();
    if (t == 0) *eflag = (s == 0) ? 1 : 0;
}

// ---------------- wa = W @ ka  (fp32, exact score path) ----------------------
__global__ void __launch_bounds__(256) wa_kernel(const float* __restrict__ W,
                                                 const float* __restrict__ KA,
                                                 float* __restrict__ wa) {
    int t = threadIdx.x;
    int half = t >> 7, k = t & 127;
    const float* kav = KA + half * 128;
    const float* wrow = W + k * 128;
    float s = 0.0f;
#pragma unroll 8
    for (int n = 0; n < 128; n++) s += wrow[n] * kav[n];
    wa[half * 128 + k] = s;
}

// ---------------- h = X @ W : tiled fp32 VALU GEMM -> bf16 H -----------------
// M-tile 64, N-tile 32, K=128; 256 threads, 4 rows x 2 cols each.
__global__ void __launch_bounds__(256) gemm_v_kernel(const float* __restrict__ X,
                                                     const float* __restrict__ W,
                                                     ushort_t* __restrict__ H, int M) {
    __shared__ float Xl[64 * 132];
    __shared__ float Wl[32 * 132];
    int t = threadIdx.x;
    int rbase = blockIdx.x * 64;
    int n0 = blockIdx.y * 32;

    for (int s = t; s < 64 * 32; s += 256) {
        int row = s >> 5, c4 = s & 31;
        int gr = rbase + row; if (gr >= M) gr = M - 1;
        *(float4*)&Xl[row * 132 + c4 * 4] = *(const float4*)&X[(size_t)gr * 128 + c4 * 4];
    }
    for (int s = t; s < 32 * 128; s += 256) {
        int k = s >> 5, c = s & 31;
        Wl[c * 132 + k] = W[k * 128 + n0 + c];
    }
    __syncthreads();

    int c0 = (t & 15) * 2;
    int r0 = (t >> 4) * 4;
    float acc[4][2] = {};
#pragma unroll 4
    for (int k = 0; k < 128; k += 4) {
        float4 xv[4], wv[2];
#pragma unroll
        for (int i = 0; i < 4; i++) xv[i] = *(const float4*)&Xl[(r0 + i) * 132 + k];
#pragma unroll
        for (int j = 0; j < 2; j++) wv[j] = *(const float4*)&Wl[(c0 + j) * 132 + k];
#pragma unroll
        for (int i = 0; i < 4; i++)
#pragma unroll
            for (int j = 0; j < 2; j++) {
                acc[i][j] += xv[i].x * wv[j].x + xv[i].y * wv[j].y
                           + xv[i].z * wv[j].z + xv[i].w * wv[j].w;
            }
    }
#pragma unroll
    for (int i = 0; i < 4; i++) {
        int grow = rbase + r0 + i;
        if (grow < M) {
            uint32_t o = (uint32_t)f2bf(acc[i][0]) | ((uint32_t)f2bf(acc[i][1]) << 16);
            *(uint32_t*)&H[(size_t)grow * 128 + n0 + c0] = o;
        }
    }
}

// ---------------- per-node scores in fp32 ------------------------------------
__global__ void __launch_bounds__(256) score_kernel(const float* __restrict__ X,
                                                    const float* __restrict__ wa,
                                                    float* __restrict__ st, float* __restrict__ ss,
                                                    int n) {
    int wave = threadIdx.x >> 6, lane = threadIdx.x & 63;
    int node = blockIdx.x * 4 + wave;
    if (node >= n) return;
    float2 x = *(const float2*)(X + (size_t)node * D + lane * 2);
    float2 wt = *(const float2*)(wa + lane * 2);
    float2 ws = *(const float2*)(wa + 128 + lane * 2);
    float s_t = x.x * wt.x + x.y * wt.y;
    float s_s = x.x * ws.x + x.y * ws.y;
#pragma unroll
    for (int off = 32; off; off >>= 1) {
        s_t += __shfl_xor(s_t, off);
        s_s += __shfl_xor(s_s, off);
    }
    if (lane == 0) { st[node] = s_t; ss[node] = s_s; }
}

// ---------------- CSR count (clamped for safety) -----------------------------
__global__ void count_kernel(const int* __restrict__ E, const int* __restrict__ eflag,
                             int* __restrict__ cnt, int ne) {
    int i = blockIdx.x * blockDim.x + threadIdx.x;
    if (i >= ne) return;
    int i64 = *eflag;                          // wave-uniform
    int tgt = i64 ? E[i * 4] : E[i * 2];
    if ((unsigned)tgt >= (unsigned)N_NODES) tgt = 0;
    atomicAdd(&cnt[tgt], 1);
}

// ---------------- single-block exclusive scan; re-zeroes cnt -----------------
__global__ void __launch_bounds__(1024) scan_kernel(int* __restrict__ cnt,
                                                    int* __restrict__ row_ptr, int n) {
    __shared__ int lds[1024];
    int t = threadIdx.x;
    int chunk = (n + 1023) / 1024;
    int base = t * chunk;
    int s = 0;
    for (int i = 0; i < chunk; i++) { int idx = base + i; if (idx < n) s += cnt[idx]; }
    lds[t] = s;
    __syncthreads();
    for (int off = 1; off < 1024; off <<= 1) {
        int v = (t >= off) ? lds[t - off] : 0;
        __syncthreads();
        lds[t] += v;
        __syncthreads();
    }
    int excl = (t == 0) ? 0 : lds[t - 1];
    for (int i = 0; i < chunk; i++) {
        int idx = base + i;
        if (idx < n) { row_ptr[idx] = excl; excl += cnt[idx]; cnt[idx] = 0; }
    }
    if (t == 1023) row_ptr[n] = lds[1023];
}

// ---------------- fill CSR + sum_e (cursor = re-zeroed cnt) ------------------
__global__ void fill_kernel(const int* __restrict__ E, const int* __restrict__ eflag,
                            const int* __restrict__ rowp, int* __restrict__ cnt,
                            const float* __restrict__ st, const float* __restrict__ ss,
                            float* __restrict__ sum_e, int* __restrict__ csr_src, int ne) {
    int i = blockIdx.x * blockDim.x + threadIdx.x;
    if (i >= ne) return;
    int i64 = *eflag;                          // wave-uniform
    int tgt, src;
    if (i64) { tgt = E[i * 4]; src = E[i * 4 + 2]; }
    else     { tgt = E[i * 2]; src = E[i * 2 + 1]; }
    if ((unsigned)tgt >= (unsigned)N_NODES) tgt = 0;
    if ((unsigned)src >= (unsigned)N_NODES) src = 0;
    float e = edge_e(st[tgt] + ss[src]);
    int pos = rowp[tgt] + atomicAdd(&cnt[tgt], 1);
    csr_src[pos] = src;
    atomicAdd(&sum_e[tgt], e);
}

// ---------------- aggregation: one wave per target node, fp32 output ---------
__global__ void __launch_bounds__(256) agg_kernel(const int* __restrict__ row_ptr,
                                                  const int* __restrict__ csr_src,
                                                  const float* __restrict__ st,
                                                  const float* __restrict__ ss,
                                                  const float* __restrict__ sum_e,
                                                  const ushort_t* __restrict__ H,
                                                  float* __restrict__ out, int n) {
    int wave = threadIdx.x >> 6, lane = threadIdx.x & 63;
    int node = blockIdx.x * 4 + wave;
    if (node >= n) return;
    node = __builtin_amdgcn_readfirstlane(node);  // scalarize row_ptr/sum_e/st loads
    int start = row_ptr[node], end = row_ptr[node + 1];
    float inv = 1.0f / (sum_e[node] + 1e-9f);
    float stn = st[node];
    float a0 = 0.0f, a1 = 0.0f;
    int col = lane * 2;
    for (int m = start; m < end; m++) {
        int src = csr_src[m];                     // wave-uniform
        float w = edge_e(stn + ss[src]) * inv;    // wave-uniform, bitwise == fill's e
        uint32_t p = *(const uint32_t*)(H + (size_t)src * D + col);  // 256B/wave
        a0 += w * bf2f(p & 0xffff);
        a1 += w * bf2f(p >> 16);
    }
    *(float2*)(out + (size_t)node * D + col) = make_float2(a0, a1);  // fp32!
}

extern "C" void kernel_launch(void* const* d_in, const int* in_sizes, int n_in,
                              void* d_out, int out_size, void* d_ws, size_t ws_size,
                              hipStream_t stream) {
    // Identify inputs by element count (all four are distinct); positional
    // defaults per setup_inputs order.
    const float* X  = (const float*)d_in[0];
    const int*   E  = (const int*)d_in[1];
    const float* W  = (const float*)d_in[2];
    const float* KA = (const float*)d_in[3];
    for (int i = 0; i < n_in; i++) {
        int s = in_sizes[i];
        if (s == N_NODES * D)      X  = (const float*)d_in[i];
        else if (s == N_EDGES * 2) E  = (const int*)d_in[i];
        else if (s == D * D)       W  = (const float*)d_in[i];
        else if (s == 2 * D)       KA = (const float*)d_in[i];
    }
    float* out = (float*)d_out;                // fp32 [100000,128]  <-- the fix

    char* ws = (char*)d_ws;
    // workspace layout (16B aligned), total ~34.0 MB (proven available)
    ushort_t* H        = (ushort_t*)(ws + 0);           // 25,600,000 B (bf16 h)
    float*    wa       = (float*)   (ws + 25600000);    //      1,024 B
    float*    st       = (float*)   (ws + 25601024);    //    400,000 B
    float*    ssb      = (float*)   (ws + 26001024);    //    400,000 B
    int*      cnt      = (int*)     (ws + 26401024);    //    400,000 B
    int*      rowp     = (int*)     (ws + 26801024);    //    400,016 B
    int*      csrs     = (int*)     (ws + 27201040);    //  6,400,000 B
    float*    sume     = (float*)   (ws + 33601040);    //    400,000 B
    int*      eflag    = (int*)     (ws + 34001040);    //         16 B

    const int NB_NODE = (N_NODES + 255) / 256;          // 391
    const int NB_WAVE = (N_NODES + 3) / 4;              // 25000 (1 wave/node)
    const int NB_EDGE = (N_EDGES + 255) / 256;          // 6250
    dim3 gemm_grid((N_NODES + 63) / 64, 4);             // 1563 x 4

    zero_kernel<<<NB_NODE, 256, 0, stream>>>(cnt, sume, N_NODES);
    detect_kernel<<<1, 256, 0, stream>>>(E, eflag);
    wa_kernel<<<1, 256, 0, stream>>>(W, KA, wa);
    gemm_v_kernel<<<gemm_grid, 256, 0, stream>>>(X, W, H, N_NODES);
    score_kernel<<<NB_WAVE, 256, 0, stream>>>(X, wa, st, ssb, N_NODES);
    count_kernel<<<NB_EDGE, 256, 0, stream>>>(E, eflag, cnt, N_EDGES);
    scan_kernel<<<1, 1024, 0, stream>>>(cnt, rowp, N_NODES);
    fill_kernel<<<NB_EDGE, 256, 0, stream>>>(E, eflag, rowp, cnt, st, ssb, sume,
                                             csrs, N_EDGES);
    agg_kernel<<<NB_WAVE, 256, 0, stream>>>(rowp, csrs, st, ssb, sume, H, out, N_NODES);
}

// Round 9
// 551.242 us; speedup vs baseline: 1.4355x; 1.4355x over previous
//
#include <hip/hip_runtime.h>
#include <stdint.h>

typedef unsigned short ushort_t;

#define N_NODES 100000
#define N_EDGES 1600000
#define D 128

static __device__ __forceinline__ float bf2f(uint32_t u) {
    return __builtin_bit_cast(float, u << 16);
}
static __device__ __forceinline__ ushort_t f2bf(float f) {
    uint32_t u = __builtin_bit_cast(uint32_t, f);
    uint32_t r = u + 0x7fffu + ((u >> 16) & 1u);   // RNE
    return (ushort_t)(r >> 16);
}
// leaky_relu(0.2) -> clip(-2,2) -> exp.  Shared by fill & agg so the
// recomputed e in agg is bitwise identical to the one summed into sum_e.
static __device__ __forceinline__ float edge_e(float s) {
    float x = (s >= 0.0f) ? s : 0.2f * s;
    x = fminf(fmaxf(x, -2.0f), 2.0f);
    return __expf(x);
}

// ---------------- zero cnt + sum_e (ws is poisoned 0xAA every call) ----------
__global__ void zero_kernel(int* cnt, float* sum_e, int n) {
    int i = blockIdx.x * blockDim.x + threadIdx.x;
    if (i < n) { cnt[i] = 0; sum_e[i] = 0.0f; }
}

// ---------------- edge dtype: int64 (odd words all 0) vs int32 ---------------
__global__ void detect_kernel(const int* __restrict__ E, int* __restrict__ eflag) {
    __shared__ int s;
    int t = threadIdx.x;
    if (t == 0) s = 0;
    __syncthreads();
    int nz = 0;
#pragma unroll
    for (int j = 0; j < 8; j++) {
        if (E[(t + j * 256) * 2 + 1] != 0) nz = 1;
    }
    if (nz) atomicOr(&s, 1);
    __syncthreads();
    if (t == 0) *eflag = (s == 0) ? 1 : 0;
}

// ---------------- wa = W @ ka  (fp32, exact score path) ----------------------
__global__ void __launch_bounds__(256) wa_kernel(const float* __restrict__ W,
                                                 const float* __restrict__ KA,
                                                 float* __restrict__ wa) {
    int t = threadIdx.x;
    int half = t >> 7, k = t & 127;
    const float* kav = KA + half * 128;
    const float* wrow = W + k * 128;
    float s = 0.0f;
#pragma unroll 8
    for (int n = 0; n < 128; n++) s += wrow[n] * kav[n];
    wa[half * 128 + k] = s;
}

// ---------------- h = X @ W : tiled fp32 VALU GEMM -> bf16 H -----------------
// M-tile 64, N-tile 32, K=128; 256 threads, 4 rows x 2 cols each.
__global__ void __launch_bounds__(256) gemm_v_kernel(const float* __restrict__ X,
                                                     const float* __restrict__ W,
                                                     ushort_t* __restrict__ H, int M) {
    __shared__ float Xl[64 * 132];
    __shared__ float Wl[32 * 132];
    int t = threadIdx.x;
    int rbase = blockIdx.x * 64;
    int n0 = blockIdx.y * 32;

    for (int s = t; s < 64 * 32; s += 256) {
        int row = s >> 5, c4 = s & 31;
        int gr = rbase + row; if (gr >= M) gr = M - 1;
        *(float4*)&Xl[row * 132 + c4 * 4] = *(const float4*)&X[(size_t)gr * 128 + c4 * 4];
    }
    for (int s = t; s < 32 * 128; s += 256) {
        int k = s >> 5, c = s & 31;
        Wl[c * 132 + k] = W[k * 128 + n0 + c];
    }
    __syncthreads();

    int c0 = (t & 15) * 2;
    int r0 = (t >> 4) * 4;
    float acc[4][2] = {};
#pragma unroll 4
    for (int k = 0; k < 128; k += 4) {
        float4 xv[4], wv[2];
#pragma unroll
        for (int i = 0; i < 4; i++) xv[i] = *(const float4*)&Xl[(r0 + i) * 132 + k];
#pragma unroll
        for (int j = 0; j < 2; j++) wv[j] = *(const float4*)&Wl[(c0 + j) * 132 + k];
#pragma unroll
        for (int i = 0; i < 4; i++)
#pragma unroll
            for (int j = 0; j < 2; j++) {
                acc[i][j] += xv[i].x * wv[j].x + xv[i].y * wv[j].y
                           + xv[i].z * wv[j].z + xv[i].w * wv[j].w;
            }
    }
#pragma unroll
    for (int i = 0; i < 4; i++) {
        int grow = rbase + r0 + i;
        if (grow < M) {
            uint32_t o = (uint32_t)f2bf(acc[i][0]) | ((uint32_t)f2bf(acc[i][1]) << 16);
            *(uint32_t*)&H[(size_t)grow * 128 + n0 + c0] = o;
        }
    }
}

// ---------------- per-node scores in fp32 ------------------------------------
__global__ void __launch_bounds__(256) score_kernel(const float* __restrict__ X,
                                                    const float* __restrict__ wa,
                                                    float* __restrict__ st, float* __restrict__ ss,
                                                    int n) {
    int wave = threadIdx.x >> 6, lane = threadIdx.x & 63;
    int node = blockIdx.x * 4 + wave;
    if (node >= n) return;
    float2 x = *(const float2*)(X + (size_t)node * D + lane * 2);
    float2 wt = *(const float2*)(wa + lane * 2);
    float2 ws = *(const float2*)(wa + 128 + lane * 2);
    float s_t = x.x * wt.x + x.y * wt.y;
    float s_s = x.x * ws.x + x.y * ws.y;
#pragma unroll
    for (int off = 32; off; off >>= 1) {
        s_t += __shfl_xor(s_t, off);
        s_s += __shfl_xor(s_s, off);
    }
    if (lane == 0) { st[node] = s_t; ss[node] = s_s; }
}

// ---------------- CSR count (clamped for safety) -----------------------------
__global__ void count_kernel(const int* __restrict__ E, const int* __restrict__ eflag,
                             int* __restrict__ cnt, int ne) {
    int i = blockIdx.x * blockDim.x + threadIdx.x;
    if (i >= ne) return;
    int i64 = *eflag;                          // wave-uniform
    int tgt = i64 ? E[i * 4] : E[i * 2];
    if ((unsigned)tgt >= (unsigned)N_NODES) tgt = 0;
    atomicAdd(&cnt[tgt], 1);
}

// ---------------- multi-block scan, pass 1: block-local exclusive ------------
// Also re-zeroes cnt (fill uses it as its cursor).
__global__ void __launch_bounds__(256) scan1_kernel(int* __restrict__ cnt,
                                                    int* __restrict__ rowp,
                                                    int* __restrict__ bsum, int n) {
    __shared__ int lds[256];
    int t = threadIdx.x;
    int i = blockIdx.x * 256 + t;
    int v = (i < n) ? cnt[i] : 0;
    if (i < n) cnt[i] = 0;
    lds[t] = v;
    __syncthreads();
    for (int off = 1; off < 256; off <<= 1) {        // Hillis-Steele inclusive
        int x = (t >= off) ? lds[t - off] : 0;
        __syncthreads();
        lds[t] += x;
        __syncthreads();
    }
    if (i < n) rowp[i] = lds[t] - v;                 // exclusive
    if (t == 255) bsum[blockIdx.x] = lds[255];       // block total
}

// ---------------- scan pass 2: scan the 391 block sums (1 block) -------------
__global__ void __launch_bounds__(512) scan2_kernel(int* __restrict__ bsum,
                                                    int* __restrict__ rowp,
                                                    int nb, int n) {
    __shared__ int lds[512];
    int t = threadIdx.x;
    int v = (t < nb) ? bsum[t] : 0;
    lds[t] = v;
    __syncthreads();
    for (int off = 1; off < 512; off <<= 1) {
        int x = (t >= off) ? lds[t - off] : 0;
        __syncthreads();
        lds[t] += x;
        __syncthreads();
    }
    if (t < nb) bsum[t] = lds[t] - v;                // exclusive block offset
    if (t == nb - 1) rowp[n] = lds[t];               // grand total = N_EDGES
}

// ---------------- scan pass 3: add block offsets -----------------------------
__global__ void __launch_bounds__(256) scan3_kernel(int* __restrict__ rowp,
                                                    const int* __restrict__ bsum, int n) {
    int i = blockIdx.x * 256 + threadIdx.x;
    if (i < n) rowp[i] += bsum[blockIdx.x];
}

// ---------------- fill CSR + sum_e (cursor = re-zeroed cnt) ------------------
__global__ void fill_kernel(const int* __restrict__ E, const int* __restrict__ eflag,
                            const int* __restrict__ rowp, int* __restrict__ cnt,
                            const float* __restrict__ st, const float* __restrict__ ss,
                            float* __restrict__ sum_e, int* __restrict__ csr_src, int ne) {
    int i = blockIdx.x * blockDim.x + threadIdx.x;
    if (i >= ne) return;
    int i64 = *eflag;                          // wave-uniform
    int tgt, src;
    if (i64) { tgt = E[i * 4]; src = E[i * 4 + 2]; }
    else     { tgt = E[i * 2]; src = E[i * 2 + 1]; }
    if ((unsigned)tgt >= (unsigned)N_NODES) tgt = 0;
    if ((unsigned)src >= (unsigned)N_NODES) src = 0;
    float e = edge_e(st[tgt] + ss[src]);
    int pos = rowp[tgt] + atomicAdd(&cnt[tgt], 1);
    csr_src[pos] = src;
    atomicAdd(&sum_e[tgt], e);
}

// ---------------- aggregation: one wave per target node, fp32 output ---------
__global__ void __launch_bounds__(256) agg_kernel(const int* __restrict__ row_ptr,
                                                  const int* __restrict__ csr_src,
                                                  const float* __restrict__ st,
                                                  const float* __restrict__ ss,
                                                  const float* __restrict__ sum_e,
                                                  const ushort_t* __restrict__ H,
                                                  float* __restrict__ out, int n) {
    int wave = threadIdx.x >> 6, lane = threadIdx.x & 63;
    int node = blockIdx.x * 4 + wave;
    if (node >= n) return;
    node = __builtin_amdgcn_readfirstlane(node);  // scalarize row_ptr/sum_e/st loads
    int start = row_ptr[node], end = row_ptr[node + 1];
    float inv = 1.0f / (sum_e[node] + 1e-9f);
    float stn = st[node];
    float a0 = 0.0f, a1 = 0.0f;
    int col = lane * 2;
    for (int m = start; m < end; m++) {
        int src = csr_src[m];                     // wave-uniform
        float w = edge_e(stn + ss[src]) * inv;    // wave-uniform, bitwise == fill's e
        uint32_t p = *(const uint32_t*)(H + (size_t)src * D + col);  // 256B/wave
        a0 += w * bf2f(p & 0xffff);
        a1 += w * bf2f(p >> 16);
    }
    *(float2*)(out + (size_t)node * D + col) = make_float2(a0, a1);
}

extern "C" void kernel_launch(void* const* d_in, const int* in_sizes, int n_in,
                              void* d_out, int out_size, void* d_ws, size_t ws_size,
                              hipStream_t stream) {
    const float* X  = (const float*)d_in[0];
    const int*   E  = (const int*)d_in[1];
    const float* W  = (const float*)d_in[2];
    const float* KA = (const float*)d_in[3];
    for (int i = 0; i < n_in; i++) {
        int s = in_sizes[i];
        if (s == N_NODES * D)      X  = (const float*)d_in[i];
        else if (s == N_EDGES * 2) E  = (const int*)d_in[i];
        else if (s == D * D)       W  = (const float*)d_in[i];
        else if (s == 2 * D)       KA = (const float*)d_in[i];
    }
    float* out = (float*)d_out;                // fp32 [100000,128]

    char* ws = (char*)d_ws;
    // workspace layout (16B aligned), total ~34.0 MB
    ushort_t* H        = (ushort_t*)(ws + 0);           // 25,600,000 B (bf16 h)
    float*    wa       = (float*)   (ws + 25600000);    //      1,024 B
    float*    st       = (float*)   (ws + 25601024);    //    400,000 B
    float*    ssb      = (float*)   (ws + 26001024);    //    400,000 B
    int*      cnt      = (int*)     (ws + 26401024);    //    400,000 B
    int*      rowp     = (int*)     (ws + 26801024);    //    400,016 B
    int*      csrs     = (int*)     (ws + 27201040);    //  6,400,000 B
    float*    sume     = (float*)   (ws + 33601040);    //    400,000 B
    int*      eflag    = (int*)     (ws + 34001040);    //         16 B
    int*      bsum     = (int*)     (ws + 34001056);    //      1,600 B

    const int NB_NODE = (N_NODES + 255) / 256;          // 391
    const int NB_WAVE = (N_NODES + 3) / 4;              // 25000 (1 wave/node)
    const int NB_EDGE = (N_EDGES + 255) / 256;          // 6250
    dim3 gemm_grid((N_NODES + 63) / 64, 4);             // 1563 x 4

    zero_kernel<<<NB_NODE, 256, 0, stream>>>(cnt, sume, N_NODES);
    detect_kernel<<<1, 256, 0, stream>>>(E, eflag);
    wa_kernel<<<1, 256, 0, stream>>>(W, KA, wa);
    gemm_v_kernel<<<gemm_grid, 256, 0, stream>>>(X, W, H, N_NODES);
    score_kernel<<<NB_WAVE, 256, 0, stream>>>(X, wa, st, ssb, N_NODES);
    count_kernel<<<NB_EDGE, 256, 0, stream>>>(E, eflag, cnt, N_EDGES);
    scan1_kernel<<<NB_NODE, 256, 0, stream>>>(cnt, rowp, bsum, N_NODES);
    scan2_kernel<<<1, 512, 0, stream>>>(bsum, rowp, NB_NODE, N_NODES);
    scan3_kernel<<<NB_NODE, 256, 0, stream>>>(rowp, bsum, N_NODES);
    fill_kernel<<<NB_EDGE, 256, 0, stream>>>(E, eflag, rowp, cnt, st, ssb, sume,
                                             csrs, N_EDGES);
    agg_kernel<<<NB_WAVE, 256, 0, stream>>>(rowp, csrs, st, ssb, sume, H, out, N_NODES);
}

// Round 10
// 434.036 us; speedup vs baseline: 1.8231x; 1.2700x over previous
//
#include <hip/hip_runtime.h>
#include <stdint.h>

typedef unsigned short ushort_t;

#define N_NODES 100000
#define N_EDGES 1600000
#define D 128

static __device__ __forceinline__ float bf2f(uint32_t u) {
    return __builtin_bit_cast(float, u << 16);
}
static __device__ __forceinline__ ushort_t f2bf(float f) {
    uint32_t u = __builtin_bit_cast(uint32_t, f);
    uint32_t r = u + 0x7fffu + ((u >> 16) & 1u);   // RNE
    return (ushort_t)(r >> 16);
}
// leaky_relu(0.2) -> clip(-2,2) -> exp
static __device__ __forceinline__ float edge_e(float s) {
    float x = (s >= 0.0f) ? s : 0.2f * s;
    x = fminf(fmaxf(x, -2.0f), 2.0f);
    return __expf(x);
}

// ---------------- zero cnt (ws is poisoned 0xAA every call) ------------------
__global__ void zero_kernel(int* cnt, int n) {
    int i = blockIdx.x * blockDim.x + threadIdx.x;
    if (i < n) cnt[i] = 0;
}

// ---------------- edge dtype: int64 (odd words all 0) vs int32 ---------------
__global__ void detect_kernel(const int* __restrict__ E, int* __restrict__ eflag) {
    __shared__ int s;
    int t = threadIdx.x;
    if (t == 0) s = 0;
    __syncthreads();
    int nz = 0;
#pragma unroll
    for (int j = 0; j < 8; j++) {
        if (E[(t + j * 256) * 2 + 1] != 0) nz = 1;
    }
    if (nz) atomicOr(&s, 1);
    __syncthreads();
    if (t == 0) *eflag = (s == 0) ? 1 : 0;
}

// ---------------- wa = W @ ka  (fp32, exact score path) ----------------------
__global__ void __launch_bounds__(256) wa_kernel(const float* __restrict__ W,
                                                 const float* __restrict__ KA,
                                                 float* __restrict__ wa) {
    int t = threadIdx.x;
    int half = t >> 7, k = t & 127;
    const float* kav = KA + half * 128;
    const float* wrow = W + k * 128;
    float s = 0.0f;
#pragma unroll 8
    for (int n = 0; n < 128; n++) s += wrow[n] * kav[n];
    wa[half * 128 + k] = s;
}

// ---------------- h = X @ W : tiled fp32 VALU GEMM -> bf16 H -----------------
__global__ void __launch_bounds__(256) gemm_v_kernel(const float* __restrict__ X,
                                                     const float* __restrict__ W,
                                                     ushort_t* __restrict__ H, int M) {
    __shared__ float Xl[64 * 132];
    __shared__ float Wl[32 * 132];
    int t = threadIdx.x;
    int rbase = blockIdx.x * 64;
    int n0 = blockIdx.y * 32;

    for (int s = t; s < 64 * 32; s += 256) {
        int row = s >> 5, c4 = s & 31;
        int gr = rbase + row; if (gr >= M) gr = M - 1;
        *(float4*)&Xl[row * 132 + c4 * 4] = *(const float4*)&X[(size_t)gr * 128 + c4 * 4];
    }
    for (int s = t; s < 32 * 128; s += 256) {
        int k = s >> 5, c = s & 31;
        Wl[c * 132 + k] = W[k * 128 + n0 + c];
    }
    __syncthreads();

    int c0 = (t & 15) * 2;
    int r0 = (t >> 4) * 4;
    float acc[4][2] = {};
#pragma unroll 4
    for (int k = 0; k < 128; k += 4) {
        float4 xv[4], wv[2];
#pragma unroll
        for (int i = 0; i < 4; i++) xv[i] = *(const float4*)&Xl[(r0 + i) * 132 + k];
#pragma unroll
        for (int j = 0; j < 2; j++) wv[j] = *(const float4*)&Wl[(c0 + j) * 132 + k];
#pragma unroll
        for (int i = 0; i < 4; i++)
#pragma unroll
            for (int j = 0; j < 2; j++) {
                acc[i][j] += xv[i].x * wv[j].x + xv[i].y * wv[j].y
                           + xv[i].z * wv[j].z + xv[i].w * wv[j].w;
            }
    }
#pragma unroll
    for (int i = 0; i < 4; i++) {
        int grow = rbase + r0 + i;
        if (grow < M) {
            uint32_t o = (uint32_t)f2bf(acc[i][0]) | ((uint32_t)f2bf(acc[i][1]) << 16);
            *(uint32_t*)&H[(size_t)grow * 128 + n0 + c0] = o;
        }
    }
}

// ---------------- per-node scores in fp32 ------------------------------------
__global__ void __launch_bounds__(256) score_kernel(const float* __restrict__ X,
                                                    const float* __restrict__ wa,
                                                    float* __restrict__ st, float* __restrict__ ss,
                                                    int n) {
    int wave = threadIdx.x >> 6, lane = threadIdx.x & 63;
    int node = blockIdx.x * 4 + wave;
    if (node >= n) return;
    float2 x = *(const float2*)(X + (size_t)node * D + lane * 2);
    float2 wt = *(const float2*)(wa + lane * 2);
    float2 ws = *(const float2*)(wa + 128 + lane * 2);
    float s_t = x.x * wt.x + x.y * wt.y;
    float s_s = x.x * ws.x + x.y * ws.y;
#pragma unroll
    for (int off = 32; off; off >>= 1) {
        s_t += __shfl_xor(s_t, off);
        s_s += __shfl_xor(s_s, off);
    }
    if (lane == 0) { st[node] = s_t; ss[node] = s_s; }
}

// ---------------- CSR count; atomic return value IS the edge's rank ----------
__global__ void count_kernel(const int* __restrict__ E, const int* __restrict__ eflag,
                             int* __restrict__ cnt, int* __restrict__ rank, int ne) {
    int i = blockIdx.x * blockDim.x + threadIdx.x;
    if (i >= ne) return;
    int i64 = *eflag;                          // wave-uniform
    int tgt = i64 ? E[i * 4] : E[i * 2];
    if ((unsigned)tgt >= (unsigned)N_NODES) tgt = 0;
    rank[i] = atomicAdd(&cnt[tgt], 1);
}

// ---------------- multi-block scan, pass 1: block-local exclusive ------------
__global__ void __launch_bounds__(256) scan1_kernel(const int* __restrict__ cnt,
                                                    int* __restrict__ rowp,
                                                    int* __restrict__ bsum, int n) {
    __shared__ int lds[256];
    int t = threadIdx.x;
    int i = blockIdx.x * 256 + t;
    int v = (i < n) ? cnt[i] : 0;
    lds[t] = v;
    __syncthreads();
    for (int off = 1; off < 256; off <<= 1) {        // Hillis-Steele inclusive
        int x = (t >= off) ? lds[t - off] : 0;
        __syncthreads();
        lds[t] += x;
        __syncthreads();
    }
    if (i < n) rowp[i] = lds[t] - v;                 // exclusive
    if (t == 255) bsum[blockIdx.x] = lds[255];       // block total
}

// ---------------- scan pass 2: scan the 391 block sums (1 block) -------------
__global__ void __launch_bounds__(512) scan2_kernel(int* __restrict__ bsum,
                                                    int* __restrict__ rowp,
                                                    int nb, int n) {
    __shared__ int lds[512];
    int t = threadIdx.x;
    int v = (t < nb) ? bsum[t] : 0;
    lds[t] = v;
    __syncthreads();
    for (int off = 1; off < 512; off <<= 1) {
        int x = (t >= off) ? lds[t - off] : 0;
        __syncthreads();
        lds[t] += x;
        __syncthreads();
    }
    if (t < nb) bsum[t] = lds[t] - v;                // exclusive block offset
    if (t == nb - 1) rowp[n] = lds[t];               // grand total
}

// ---------------- scan pass 3: add block offsets -----------------------------
__global__ void __launch_bounds__(256) scan3_kernel(int* __restrict__ rowp,
                                                    const int* __restrict__ bsum, int n) {
    int i = blockIdx.x * 256 + threadIdx.x;
    if (i < n) rowp[i] += bsum[blockIdx.x];
}

// ---------------- fill CSR: ATOMIC-FREE (pos = rowp[tgt] + rank[i]) ----------
__global__ void fill_kernel(const int* __restrict__ E, const int* __restrict__ eflag,
                            const int* __restrict__ rowp, const int* __restrict__ rank,
                            int* __restrict__ csr_src, int ne) {
    int i = blockIdx.x * blockDim.x + threadIdx.x;
    if (i >= ne) return;
    int i64 = *eflag;                          // wave-uniform
    int tgt, src;
    if (i64) { tgt = E[i * 4]; src = E[i * 4 + 2]; }
    else     { tgt = E[i * 2]; src = E[i * 2 + 1]; }
    if ((unsigned)tgt >= (unsigned)N_NODES) tgt = 0;
    if ((unsigned)src >= (unsigned)N_NODES) src = 0;
    csr_src[rowp[tgt] + rank[i]] = src;
}

// ---------------- aggregation: one wave/node; sum_e folded in ----------------
// out = sum_i(e_i * h_i) / (sum_i e_i + 1e-9)  ==  reference modulo fp order
__global__ void __launch_bounds__(256) agg_kernel(const int* __restrict__ row_ptr,
                                                  const int* __restrict__ csr_src,
                                                  const float* __restrict__ st,
                                                  const float* __restrict__ ss,
                                                  const ushort_t* __restrict__ H,
                                                  float* __restrict__ out, int n) {
    int wave = threadIdx.x >> 6, lane = threadIdx.x & 63;
    int node = blockIdx.x * 4 + wave;
    if (node >= n) return;
    node = __builtin_amdgcn_readfirstlane(node);  // scalarize row_ptr/st loads
    int start = row_ptr[node], end = row_ptr[node + 1];
    float stn = st[node];
    float den = 1e-9f;
    float a0 = 0.0f, a1 = 0.0f;
    int col = lane * 2;
    for (int m = start; m < end; m++) {
        int src = csr_src[m];                     // wave-uniform
        float e = edge_e(stn + ss[src]);          // wave-uniform
        den += e;
        uint32_t p = *(const uint32_t*)(H + (size_t)src * D + col);  // 256B/wave
        a0 += e * bf2f(p & 0xffff);
        a1 += e * bf2f(p >> 16);
    }
    float inv = 1.0f / den;
    *(float2*)(out + (size_t)node * D + col) = make_float2(a0 * inv, a1 * inv);
}

extern "C" void kernel_launch(void* const* d_in, const int* in_sizes, int n_in,
                              void* d_out, int out_size, void* d_ws, size_t ws_size,
                              hipStream_t stream) {
    const float* X  = (const float*)d_in[0];
    const int*   E  = (const int*)d_in[1];
    const float* W  = (const float*)d_in[2];
    const float* KA = (const float*)d_in[3];
    for (int i = 0; i < n_in; i++) {
        int s = in_sizes[i];
        if (s == N_NODES * D)      X  = (const float*)d_in[i];
        else if (s == N_EDGES * 2) E  = (const int*)d_in[i];
        else if (s == D * D)       W  = (const float*)d_in[i];
        else if (s == 2 * D)       KA = (const float*)d_in[i];
    }
    float* out = (float*)d_out;                // fp32 [100000,128]
    // rank[] (6.4 MB) borrows the head of d_out: written by count, read by
    // fill, fully overwritten by agg afterwards (stream-ordered).
    int* rank = (int*)d_out;

    char* ws = (char*)d_ws;
    // workspace layout (16B aligned), total ~33.6 MB
    ushort_t* H        = (ushort_t*)(ws + 0);           // 25,600,000 B (bf16 h)
    float*    wa       = (float*)   (ws + 25600000);    //      1,024 B
    float*    st       = (float*)   (ws + 25601024);    //    400,000 B
    float*    ssb      = (float*)   (ws + 26001024);    //    400,000 B
    int*      cnt      = (int*)     (ws + 26401024);    //    400,000 B
    int*      rowp     = (int*)     (ws + 26801024);    //    400,016 B
    int*      csrs     = (int*)     (ws + 27201040);    //  6,400,000 B
    int*      eflag    = (int*)     (ws + 33601040);    //         16 B
    int*      bsum     = (int*)     (ws + 33601056);    //      1,600 B

    const int NB_NODE = (N_NODES + 255) / 256;          // 391
    const int NB_WAVE = (N_NODES + 3) / 4;              // 25000 (1 wave/node)
    const int NB_EDGE = (N_EDGES + 255) / 256;          // 6250
    dim3 gemm_grid((N_NODES + 63) / 64, 4);             // 1563 x 4

    zero_kernel<<<NB_NODE, 256, 0, stream>>>(cnt, N_NODES);
    detect_kernel<<<1, 256, 0, stream>>>(E, eflag);
    wa_kernel<<<1, 256, 0, stream>>>(W, KA, wa);
    gemm_v_kernel<<<gemm_grid, 256, 0, stream>>>(X, W, H, N_NODES);
    score_kernel<<<NB_WAVE, 256, 0, stream>>>(X, wa, st, ssb, N_NODES);
    count_kernel<<<NB_EDGE, 256, 0, stream>>>(E, eflag, cnt, rank, N_EDGES);
    scan1_kernel<<<NB_NODE, 256, 0, stream>>>(cnt, rowp, bsum, N_NODES);
    scan2_kernel<<<1, 512, 0, stream>>>(bsum, rowp, NB_NODE, N_NODES);
    scan3_kernel<<<NB_NODE, 256, 0, stream>>>(rowp, bsum, N_NODES);
    fill_kernel<<<NB_EDGE, 256, 0, stream>>>(E, eflag, rowp, rank, csrs, N_EDGES);
    agg_kernel<<<NB_WAVE, 256, 0, stream>>>(rowp, csrs, st, ssb, H, out, N_NODES);
}

// Round 11
// 343.618 us; speedup vs baseline: 2.3028x; 1.2631x over previous
//
#include <hip/hip_runtime.h>
#include <stdint.h>

typedef unsigned short ushort_t;
typedef __attribute__((ext_vector_type(8))) short short8;   // 8 bf16 = 4 VGPRs
typedef __attribute__((ext_vector_type(4))) float float4v;  // MFMA acc

#define N_NODES 100000
#define N_EDGES 1600000
#define D 128

static __device__ __forceinline__ float bf2f(uint32_t u) {
    return __builtin_bit_cast(float, u << 16);
}
static __device__ __forceinline__ ushort_t f2bf(float f) {
    uint32_t u = __builtin_bit_cast(uint32_t, f);
    uint32_t r = u + 0x7fffu + ((u >> 16) & 1u);   // RNE
    return (ushort_t)(r >> 16);
}
// leaky_relu(0.2) -> clip(-2,2) -> exp
static __device__ __forceinline__ float edge_e(float s) {
    float x = (s >= 0.0f) ? s : 0.2f * s;
    x = fminf(fmaxf(x, -2.0f), 2.0f);
    return __expf(x);
}

// ---------------- zero cnt (ws is poisoned 0xAA every call) ------------------
__global__ void zero_kernel(int* cnt, int n) {
    int i = blockIdx.x * blockDim.x + threadIdx.x;
    if (i < n) cnt[i] = 0;
}

// ---------------- edge dtype: int64 (odd words all 0) vs int32 ---------------
__global__ void detect_kernel(const int* __restrict__ E, int* __restrict__ eflag) {
    __shared__ int s;
    int t = threadIdx.x;
    if (t == 0) s = 0;
    __syncthreads();
    int nz = 0;
#pragma unroll
    for (int j = 0; j < 8; j++) {
        if (E[(t + j * 256) * 2 + 1] != 0) nz = 1;
    }
    if (nz) atomicOr(&s, 1);
    __syncthreads();
    if (t == 0) *eflag = (s == 0) ? 1 : 0;
}

// ---------------- wa = W @ ka  (fp32, exact score path) ----------------------
__global__ void __launch_bounds__(256) wa_kernel(const float* __restrict__ W,
                                                 const float* __restrict__ KA,
                                                 float* __restrict__ wa) {
    int t = threadIdx.x;
    int half = t >> 7, k = t & 127;
    const float* kav = KA + half * 128;
    const float* wrow = W + k * 128;
    float s = 0.0f;
#pragma unroll 8
    for (int n = 0; n < 128; n++) s += wrow[n] * kav[n];
    wa[half * 128 + k] = s;
}

// ---------------- transpose + convert W (fp32) -> WT (bf16) ------------------
__global__ void transpose_kernel(const float* __restrict__ W, ushort_t* __restrict__ WT) {
    int i = blockIdx.x * 256 + threadIdx.x;   // 16384 elements
    int r = i >> 7, c = i & 127;              // r = k, c = n
    WT[c * 128 + r] = f2bf(W[i]);
}

// ---------------- h = X @ W : MFMA bf16 GEMM (fp32 acc) -> bf16 H ------------
// Grid 1-D over M: X fetched exactly once.  Block = 4 waves; each wave does
// 16 rows x 128 cols, K=128 via 4 kb-blocks x 8 col-tiles of 16x16x32 MFMA.
// Fragment layouts per m89/m120-verified mappings.
__global__ void __launch_bounds__(256) gemm_kernel(const float* __restrict__ X,
                                                   const ushort_t* __restrict__ WT,
                                                   ushort_t* __restrict__ H, int M) {
    __shared__ ushort_t lds_wt[128 * 136];    // rows padded +8: 2-way aliasing only
    int tid = threadIdx.x;
    for (int j = 0; j < 8; j++) {
        int chunk = tid + j * 256;            // 2048 chunks of 8 bf16
        int row = chunk >> 4, col8 = chunk & 15;
        short8 v = *(const short8*)(WT + chunk * 8);
        *(short8*)(&lds_wt[row * 136 + col8 * 8]) = v;
    }
    __syncthreads();

    int wave = tid >> 6, lane = tid & 63;
    int quad = lane >> 4, l16 = lane & 15;
    int m0 = blockIdx.x * 64 + wave * 16;

    int arow = m0 + l16; if (arow >= M) arow = M - 1;   // clamp; store guarded
    const float* xrow = X + (size_t)arow * D + quad * 8;
    short8 a[4];
#pragma unroll
    for (int kb = 0; kb < 4; kb++) {          // A[m=l16][k=kb*32+quad*8+j]
        float4 f0 = *(const float4*)(xrow + kb * 32);
        float4 f1 = *(const float4*)(xrow + kb * 32 + 4);
        short8 v;
        v[0] = (short)f2bf(f0.x); v[1] = (short)f2bf(f0.y);
        v[2] = (short)f2bf(f0.z); v[3] = (short)f2bf(f0.w);
        v[4] = (short)f2bf(f1.x); v[5] = (short)f2bf(f1.y);
        v[6] = (short)f2bf(f1.z); v[7] = (short)f2bf(f1.w);
        a[kb] = v;
    }

    float4v acc[8] = {};
#pragma unroll
    for (int kb = 0; kb < 4; kb++) {
#pragma unroll
        for (int t = 0; t < 8; t++) {         // B[k=kb*32+quad*8+j][n=t*16+l16]
            short8 b = *(const short8*)(&lds_wt[(t * 16 + l16) * 136 + kb * 32 + quad * 8]);
            acc[t] = __builtin_amdgcn_mfma_f32_16x16x32_bf16(a[kb], b, acc[t], 0, 0, 0);
        }
    }
    // C/D: col = lane&15, row = quad*4 + reg   [m89-verified]
#pragma unroll
    for (int t = 0; t < 8; t++) {
#pragma unroll
        for (int r = 0; r < 4; r++) {
            int orow = m0 + quad * 4 + r;
            if (orow < M) H[(size_t)orow * D + t * 16 + l16] = f2bf(acc[t][r]);
        }
    }
}

// ---------------- per-node scores in fp32 ------------------------------------
__global__ void __launch_bounds__(256) score_kernel(const float* __restrict__ X,
                                                    const float* __restrict__ wa,
                                                    float* __restrict__ st, float* __restrict__ ss,
                                                    int n) {
    int wave = threadIdx.x >> 6, lane = threadIdx.x & 63;
    int node = blockIdx.x * 4 + wave;
    if (node >= n) return;
    float2 x = *(const float2*)(X + (size_t)node * D + lane * 2);
    float2 wt = *(const float2*)(wa + lane * 2);
    float2 ws = *(const float2*)(wa + 128 + lane * 2);
    float s_t = x.x * wt.x + x.y * wt.y;
    float s_s = x.x * ws.x + x.y * ws.y;
#pragma unroll
    for (int off = 32; off; off >>= 1) {
        s_t += __shfl_xor(s_t, off);
        s_s += __shfl_xor(s_s, off);
    }
    if (lane == 0) { st[node] = s_t; ss[node] = s_s; }
}

// ---------------- CSR count; atomic return value IS the edge's rank ----------
__global__ void count_kernel(const int* __restrict__ E, const int* __restrict__ eflag,
                             int* __restrict__ cnt, int* __restrict__ rank, int ne) {
    int i = blockIdx.x * blockDim.x + threadIdx.x;
    if (i >= ne) return;
    int i64 = *eflag;                          // wave-uniform
    int tgt = i64 ? E[i * 4] : E[i * 2];
    if ((unsigned)tgt >= (unsigned)N_NODES) tgt = 0;
    rank[i] = atomicAdd(&cnt[tgt], 1);
}

// ---------------- multi-block scan, pass 1: block-local exclusive ------------
__global__ void __launch_bounds__(256) scan1_kernel(const int* __restrict__ cnt,
                                                    int* __restrict__ rowp,
                                                    int* __restrict__ bsum, int n) {
    __shared__ int lds[256];
    int t = threadIdx.x;
    int i = blockIdx.x * 256 + t;
    int v = (i < n) ? cnt[i] : 0;
    lds[t] = v;
    __syncthreads();
    for (int off = 1; off < 256; off <<= 1) {        // Hillis-Steele inclusive
        int x = (t >= off) ? lds[t - off] : 0;
        __syncthreads();
        lds[t] += x;
        __syncthreads();
    }
    if (i < n) rowp[i] = lds[t] - v;                 // exclusive
    if (t == 255) bsum[blockIdx.x] = lds[255];       // block total
}

// ---------------- scan pass 2: scan the 391 block sums (1 block) -------------
__global__ void __launch_bounds__(512) scan2_kernel(int* __restrict__ bsum,
                                                    int* __restrict__ rowp,
                                                    int nb, int n) {
    __shared__ int lds[512];
    int t = threadIdx.x;
    int v = (t < nb) ? bsum[t] : 0;
    lds[t] = v;
    __syncthreads();
    for (int off = 1; off < 512; off <<= 1) {
        int x = (t >= off) ? lds[t - off] : 0;
        __syncthreads();
        lds[t] += x;
        __syncthreads();
    }
    if (t < nb) bsum[t] = lds[t] - v;                // exclusive block offset
    if (t == nb - 1) rowp[n] = lds[t];               // grand total
}

// ---------------- scan pass 3: add block offsets -----------------------------
__global__ void __launch_bounds__(256) scan3_kernel(int* __restrict__ rowp,
                                                    const int* __restrict__ bsum, int n) {
    int i = blockIdx.x * 256 + threadIdx.x;
    if (i < n) rowp[i] += bsum[blockIdx.x];
}

// ---------------- fill CSR: atomic-free (pos = rowp[tgt] + rank[i]) ----------
__global__ void fill_kernel(const int* __restrict__ E, const int* __restrict__ eflag,
                            const int* __restrict__ rowp, const int* __restrict__ rank,
                            int* __restrict__ csr_src, int ne) {
    int i = blockIdx.x * blockDim.x + threadIdx.x;
    if (i >= ne) return;
    int i64 = *eflag;                          // wave-uniform
    int tgt, src;
    if (i64) { tgt = E[i * 4]; src = E[i * 4 + 2]; }
    else     { tgt = E[i * 2]; src = E[i * 2 + 1]; }
    if ((unsigned)tgt >= (unsigned)N_NODES) tgt = 0;
    if ((unsigned)src >= (unsigned)N_NODES) src = 0;
    csr_src[rowp[tgt] + rank[i]] = src;
}

// ---------------- aggregation: one wave/node; sum_e folded in ----------------
__global__ void __launch_bounds__(256) agg_kernel(const int* __restrict__ row_ptr,
                                                  const int* __restrict__ csr_src,
                                                  const float* __restrict__ st,
                                                  const float* __restrict__ ss,
                                                  const ushort_t* __restrict__ H,
                                                  float* __restrict__ out, int n) {
    int wave = threadIdx.x >> 6, lane = threadIdx.x & 63;
    int node = blockIdx.x * 4 + wave;
    if (node >= n) return;
    node = __builtin_amdgcn_readfirstlane(node);  // scalarize row_ptr/st loads
    int start = row_ptr[node], end = row_ptr[node + 1];
    float stn = st[node];
    float den = 1e-9f;
    float a0 = 0.0f, a1 = 0.0f;
    int col = lane * 2;
    for (int m = start; m < end; m++) {
        int src = csr_src[m];                     // wave-uniform
        float e = edge_e(stn + ss[src]);          // wave-uniform
        den += e;
        uint32_t p = *(const uint32_t*)(H + (size_t)src * D + col);  // 256B/wave
        a0 += e * bf2f(p & 0xffff);
        a1 += e * bf2f(p >> 16);
    }
    float inv = 1.0f / den;
    *(float2*)(out + (size_t)node * D + col) = make_float2(a0 * inv, a1 * inv);
}

extern "C" void kernel_launch(void* const* d_in, const int* in_sizes, int n_in,
                              void* d_out, int out_size, void* d_ws, size_t ws_size,
                              hipStream_t stream) {
    const float* X  = (const float*)d_in[0];
    const int*   E  = (const int*)d_in[1];
    const float* W  = (const float*)d_in[2];
    const float* KA = (const float*)d_in[3];
    for (int i = 0; i < n_in; i++) {
        int s = in_sizes[i];
        if (s == N_NODES * D)      X  = (const float*)d_in[i];
        else if (s == N_EDGES * 2) E  = (const int*)d_in[i];
        else if (s == D * D)       W  = (const float*)d_in[i];
        else if (s == 2 * D)       KA = (const float*)d_in[i];
    }
    float* out = (float*)d_out;                // fp32 [100000,128]
    int* rank = (int*)d_out;                   // 6.4 MB scratch in d_out head

    char* ws = (char*)d_ws;
    // workspace layout (16B aligned), total ~33.6 MB
    ushort_t* H        = (ushort_t*)(ws + 0);           // 25,600,000 B (bf16 h)
    float*    wa       = (float*)   (ws + 25600000);    //      1,024 B
    float*    st       = (float*)   (ws + 25601024);    //    400,000 B
    float*    ssb      = (float*)   (ws + 26001024);    //    400,000 B
    int*      cnt      = (int*)     (ws + 26401024);    //    400,000 B
    int*      rowp     = (int*)     (ws + 26801024);    //    400,016 B
    int*      csrs     = (int*)     (ws + 27201040);    //  6,400,000 B
    int*      eflag    = (int*)     (ws + 33601040);    //         16 B
    int*      bsum     = (int*)     (ws + 33601056);    //      1,600 B
    ushort_t* WT       = (ushort_t*)(ws + 33602656);    //     32,768 B

    const int NB_NODE = (N_NODES + 255) / 256;          // 391
    const int NB_WAVE = (N_NODES + 3) / 4;              // 25000 (1 wave/node)
    const int NB_EDGE = (N_EDGES + 255) / 256;          // 6250
    const int NB_GEMM = (N_NODES + 63) / 64;            // 1563

    zero_kernel<<<NB_NODE, 256, 0, stream>>>(cnt, N_NODES);
    detect_kernel<<<1, 256, 0, stream>>>(E, eflag);
    wa_kernel<<<1, 256, 0, stream>>>(W, KA, wa);
    transpose_kernel<<<64, 256, 0, stream>>>(W, WT);
    gemm_kernel<<<NB_GEMM, 256, 0, stream>>>(X, WT, H, N_NODES);
    score_kernel<<<NB_WAVE, 256, 0, stream>>>(X, wa, st, ssb, N_NODES);
    count_kernel<<<NB_EDGE, 256, 0, stream>>>(E, eflag, cnt, rank, N_EDGES);
    scan1_kernel<<<NB_NODE, 256, 0, stream>>>(cnt, rowp, bsum, N_NODES);
    scan2_kernel<<<1, 512, 0, stream>>>(bsum, rowp, NB_NODE, N_NODES);
    scan3_kernel<<<NB_NODE, 256, 0, stream>>>(rowp, bsum, N_NODES);
    fill_kernel<<<NB_EDGE, 256, 0, stream>>>(E, eflag, rowp, rank, csrs, N_EDGES);
    agg_kernel<<<NB_WAVE, 256, 0, stream>>>(rowp, csrs, st, ssb, H, out, N_NODES);
}

// Round 12
// 302.140 us; speedup vs baseline: 2.6190x; 1.1373x over previous
//
#include <hip/hip_runtime.h>
#include <stdint.h>

typedef unsigned short ushort_t;
typedef __attribute__((ext_vector_type(8))) short short8;   // 8 bf16 = 4 VGPRs
typedef __attribute__((ext_vector_type(4))) float float4v;  // MFMA acc

#define N_NODES 100000
#define N_EDGES 1600000
#define D 128

static __device__ __forceinline__ float bf2f(uint32_t u) {
    return __builtin_bit_cast(float, u << 16);
}
static __device__ __forceinline__ ushort_t f2bf(float f) {
    uint32_t u = __builtin_bit_cast(uint32_t, f);
    uint32_t r = u + 0x7fffu + ((u >> 16) & 1u);   // RNE
    return (ushort_t)(r >> 16);
}
// leaky_relu(0.2) -> clip(-2,2) -> exp
static __device__ __forceinline__ float edge_e(float s) {
    float x = (s >= 0.0f) ? s : 0.2f * s;
    x = fminf(fmaxf(x, -2.0f), 2.0f);
    return __expf(x);
}

// ---------------- zero cnt (ws is poisoned 0xAA every call) ------------------
__global__ void zero_kernel(int* cnt, int n) {
    int i = blockIdx.x * blockDim.x + threadIdx.x;
    if (i < n) cnt[i] = 0;
}

// ---------------- edge dtype: int64 (odd words all 0) vs int32 ---------------
__global__ void detect_kernel(const int* __restrict__ E, int* __restrict__ eflag) {
    __shared__ int s;
    int t = threadIdx.x;
    if (t == 0) s = 0;
    __syncthreads();
    int nz = 0;
#pragma unroll
    for (int j = 0; j < 8; j++) {
        if (E[(t + j * 256) * 2 + 1] != 0) nz = 1;
    }
    if (nz) atomicOr(&s, 1);
    __syncthreads();
    if (t == 0) *eflag = (s == 0) ? 1 : 0;
}

// ---------------- wa = W @ ka  (fp32, exact score path) ----------------------
__global__ void __launch_bounds__(256) wa_kernel(const float* __restrict__ W,
                                                 const float* __restrict__ KA,
                                                 float* __restrict__ wa) {
    int t = threadIdx.x;
    int half = t >> 7, k = t & 127;
    const float* kav = KA + half * 128;
    const float* wrow = W + k * 128;
    float s = 0.0f;
#pragma unroll 8
    for (int n = 0; n < 128; n++) s += wrow[n] * kav[n];
    wa[half * 128 + k] = s;
}

// ---------------- transpose + convert W (fp32) -> WT (bf16) ------------------
__global__ void transpose_kernel(const float* __restrict__ W, ushort_t* __restrict__ WT) {
    int i = blockIdx.x * 256 + threadIdx.x;   // 16384 elements
    int r = i >> 7, c = i & 127;              // r = k, c = n
    WT[c * 128 + r] = f2bf(W[i]);
}

// ---------------- h = X @ W : MFMA bf16 GEMM (fp32 acc) -> bf16 H ------------
__global__ void __launch_bounds__(256) gemm_kernel(const float* __restrict__ X,
                                                   const ushort_t* __restrict__ WT,
                                                   ushort_t* __restrict__ H, int M) {
    __shared__ ushort_t lds_wt[128 * 136];    // rows padded +8: 2-way aliasing only
    int tid = threadIdx.x;
    for (int j = 0; j < 8; j++) {
        int chunk = tid + j * 256;            // 2048 chunks of 8 bf16
        int row = chunk >> 4, col8 = chunk & 15;
        short8 v = *(const short8*)(WT + chunk * 8);
        *(short8*)(&lds_wt[row * 136 + col8 * 8]) = v;
    }
    __syncthreads();

    int wave = tid >> 6, lane = tid & 63;
    int quad = lane >> 4, l16 = lane & 15;
    int m0 = blockIdx.x * 64 + wave * 16;

    int arow = m0 + l16; if (arow >= M) arow = M - 1;   // clamp; store guarded
    const float* xrow = X + (size_t)arow * D + quad * 8;
    short8 a[4];
#pragma unroll
    for (int kb = 0; kb < 4; kb++) {          // A[m=l16][k=kb*32+quad*8+j]
        float4 f0 = *(const float4*)(xrow + kb * 32);
        float4 f1 = *(const float4*)(xrow + kb * 32 + 4);
        short8 v;
        v[0] = (short)f2bf(f0.x); v[1] = (short)f2bf(f0.y);
        v[2] = (short)f2bf(f0.z); v[3] = (short)f2bf(f0.w);
        v[4] = (short)f2bf(f1.x); v[5] = (short)f2bf(f1.y);
        v[6] = (short)f2bf(f1.z); v[7] = (short)f2bf(f1.w);
        a[kb] = v;
    }

    float4v acc[8] = {};
#pragma unroll
    for (int kb = 0; kb < 4; kb++) {
#pragma unroll
        for (int t = 0; t < 8; t++) {         // B[k=kb*32+quad*8+j][n=t*16+l16]
            short8 b = *(const short8*)(&lds_wt[(t * 16 + l16) * 136 + kb * 32 + quad * 8]);
            acc[t] = __builtin_amdgcn_mfma_f32_16x16x32_bf16(a[kb], b, acc[t], 0, 0, 0);
        }
    }
    // C/D: col = lane&15, row = quad*4 + reg   [m89-verified]
#pragma unroll
    for (int t = 0; t < 8; t++) {
#pragma unroll
        for (int r = 0; r < 4; r++) {
            int orow = m0 + quad * 4 + r;
            if (orow < M) H[(size_t)orow * D + t * 16 + l16] = f2bf(acc[t][r]);
        }
    }
}

// ---------------- per-node scores in fp32 ------------------------------------
__global__ void __launch_bounds__(256) score_kernel(const float* __restrict__ X,
                                                    const float* __restrict__ wa,
                                                    float* __restrict__ st, float* __restrict__ ss,
                                                    int n) {
    int wave = threadIdx.x >> 6, lane = threadIdx.x & 63;
    int node = blockIdx.x * 4 + wave;
    if (node >= n) return;
    float2 x = *(const float2*)(X + (size_t)node * D + lane * 2);
    float2 wt = *(const float2*)(wa + lane * 2);
    float2 ws = *(const float2*)(wa + 128 + lane * 2);
    float s_t = x.x * wt.x + x.y * wt.y;
    float s_s = x.x * ws.x + x.y * ws.y;
#pragma unroll
    for (int off = 32; off; off >>= 1) {
        s_t += __shfl_xor(s_t, off);
        s_s += __shfl_xor(s_s, off);
    }
    if (lane == 0) { st[node] = s_t; ss[node] = s_s; }
}

// ---------------- CSR count; atomic return value IS the edge's rank ----------
__global__ void count_kernel(const int* __restrict__ E, const int* __restrict__ eflag,
                             int* __restrict__ cnt, int* __restrict__ rank, int ne) {
    int i = blockIdx.x * blockDim.x + threadIdx.x;
    if (i >= ne) return;
    int i64 = *eflag;                          // wave-uniform
    int tgt = i64 ? E[i * 4] : E[i * 2];
    if ((unsigned)tgt >= (unsigned)N_NODES) tgt = 0;
    rank[i] = atomicAdd(&cnt[tgt], 1);
}

// ---------------- multi-block scan, pass 1: block-local exclusive ------------
__global__ void __launch_bounds__(256) scan1_kernel(const int* __restrict__ cnt,
                                                    int* __restrict__ rowp,
                                                    int* __restrict__ bsum, int n) {
    __shared__ int lds[256];
    int t = threadIdx.x;
    int i = blockIdx.x * 256 + t;
    int v = (i < n) ? cnt[i] : 0;
    lds[t] = v;
    __syncthreads();
    for (int off = 1; off < 256; off <<= 1) {        // Hillis-Steele inclusive
        int x = (t >= off) ? lds[t - off] : 0;
        __syncthreads();
        lds[t] += x;
        __syncthreads();
    }
    if (i < n) rowp[i] = lds[t] - v;                 // exclusive
    if (t == 255) bsum[blockIdx.x] = lds[255];       // block total
}

// ---------------- scan pass 2: scan the 391 block sums (1 block) -------------
__global__ void __launch_bounds__(512) scan2_kernel(int* __restrict__ bsum,
                                                    int* __restrict__ rowp,
                                                    int nb, int n) {
    __shared__ int lds[512];
    int t = threadIdx.x;
    int v = (t < nb) ? bsum[t] : 0;
    lds[t] = v;
    __syncthreads();
    for (int off = 1; off < 512; off <<= 1) {
        int x = (t >= off) ? lds[t - off] : 0;
        __syncthreads();
        lds[t] += x;
        __syncthreads();
    }
    if (t < nb) bsum[t] = lds[t] - v;                // exclusive block offset
    if (t == nb - 1) rowp[n] = lds[t];               // grand total
}

// ---------------- scan pass 3: add block offsets -----------------------------
__global__ void __launch_bounds__(256) scan3_kernel(int* __restrict__ rowp,
                                                    const int* __restrict__ bsum, int n) {
    int i = blockIdx.x * 256 + threadIdx.x;
    if (i < n) rowp[i] += bsum[blockIdx.x];
}

// ---------------- fill CSR: atomic-free (pos = rowp[tgt] + rank[i]) ----------
__global__ void fill_kernel(const int* __restrict__ E, const int* __restrict__ eflag,
                            const int* __restrict__ rowp, const int* __restrict__ rank,
                            int* __restrict__ csr_src, int ne) {
    int i = blockIdx.x * blockDim.x + threadIdx.x;
    if (i >= ne) return;
    int i64 = *eflag;                          // wave-uniform
    int tgt, src;
    if (i64) { tgt = E[i * 4]; src = E[i * 4 + 2]; }
    else     { tgt = E[i * 2]; src = E[i * 2 + 1]; }
    if ((unsigned)tgt >= (unsigned)N_NODES) tgt = 0;
    if ((unsigned)src >= (unsigned)N_NODES) src = 0;
    csr_src[rowp[tgt] + rank[i]] = src;
}

// ---------------- aggregation v2: 4 edges in flight per wave -----------------
// Wave = 4 groups x 16 lanes; group g handles edge m+g; lane l covers cols
// l*8..l*8+7 via one dwordx4 H load (256B/group, 1KB/wave per instruction).
// Cross-group reduce at the end via shfl_xor(16,32).
__global__ void __launch_bounds__(256) agg_kernel(const int* __restrict__ row_ptr,
                                                  const int* __restrict__ csr_src,
                                                  const float* __restrict__ st,
                                                  const float* __restrict__ ss,
                                                  const ushort_t* __restrict__ H,
                                                  float* __restrict__ out, int n) {
    int wave = threadIdx.x >> 6, lane = threadIdx.x & 63;
    int node = blockIdx.x * 4 + wave;
    if (node >= n) return;
    node = __builtin_amdgcn_readfirstlane(node);  // scalarize row_ptr/st loads
    int g = lane >> 4, l = lane & 15;
    int start = row_ptr[node], end = row_ptr[node + 1];
    float stn = st[node];
    float den = 0.0f;
    float acc[8] = {};
    for (int m = start + g; m < end; m += 4) {
        int src = csr_src[m];                     // group-uniform (16B/wave)
        float e = edge_e(stn + ss[src]);
        den += e;
        uint4 p = *(const uint4*)(H + (size_t)src * D + l * 8);  // 8 bf16
        acc[0] += e * bf2f(p.x & 0xffff); acc[1] += e * bf2f(p.x >> 16);
        acc[2] += e * bf2f(p.y & 0xffff); acc[3] += e * bf2f(p.y >> 16);
        acc[4] += e * bf2f(p.z & 0xffff); acc[5] += e * bf2f(p.z >> 16);
        acc[6] += e * bf2f(p.w & 0xffff); acc[7] += e * bf2f(p.w >> 16);
    }
    // reduce across the 4 groups (lanes l, l+16, l+32, l+48)
    den += __shfl_xor(den, 16);
    den += __shfl_xor(den, 32);
#pragma unroll
    for (int j = 0; j < 8; j++) {
        acc[j] += __shfl_xor(acc[j], 16);
        acc[j] += __shfl_xor(acc[j], 32);
    }
    float inv = 1.0f / (den + 1e-9f);
    if (g == 0) {                                 // 16 lanes store 512B row
        float4 o0 = make_float4(acc[0] * inv, acc[1] * inv, acc[2] * inv, acc[3] * inv);
        float4 o1 = make_float4(acc[4] * inv, acc[5] * inv, acc[6] * inv, acc[7] * inv);
        *(float4*)(out + (size_t)node * D + l * 8) = o0;
        *(float4*)(out + (size_t)node * D + l * 8 + 4) = o1;
    }
}

extern "C" void kernel_launch(void* const* d_in, const int* in_sizes, int n_in,
                              void* d_out, int out_size, void* d_ws, size_t ws_size,
                              hipStream_t stream) {
    const float* X  = (const float*)d_in[0];
    const int*   E  = (const int*)d_in[1];
    const float* W  = (const float*)d_in[2];
    const float* KA = (const float*)d_in[3];
    for (int i = 0; i < n_in; i++) {
        int s = in_sizes[i];
        if (s == N_NODES * D)      X  = (const float*)d_in[i];
        else if (s == N_EDGES * 2) E  = (const int*)d_in[i];
        else if (s == D * D)       W  = (const float*)d_in[i];
        else if (s == 2 * D)       KA = (const float*)d_in[i];
    }
    float* out = (float*)d_out;                // fp32 [100000,128]
    int* rank = (int*)d_out;                   // 6.4 MB scratch in d_out head

    char* ws = (char*)d_ws;
    // workspace layout (16B aligned), total ~33.6 MB
    ushort_t* H        = (ushort_t*)(ws + 0);           // 25,600,000 B (bf16 h)
    float*    wa       = (float*)   (ws + 25600000);    //      1,024 B
    float*    st       = (float*)   (ws + 25601024);    //    400,000 B
    float*    ssb      = (float*)   (ws + 26001024);    //    400,000 B
    int*      cnt      = (int*)     (ws + 26401024);    //    400,000 B
    int*      rowp     = (int*)     (ws + 26801024);    //    400,016 B
    int*      csrs     = (int*)     (ws + 27201040);    //  6,400,000 B
    int*      eflag    = (int*)     (ws + 33601040);    //         16 B
    int*      bsum     = (int*)     (ws + 33601056);    //      1,600 B
    ushort_t* WT       = (ushort_t*)(ws + 33602656);    //     32,768 B

    const int NB_NODE = (N_NODES + 255) / 256;          // 391
    const int NB_WAVE = (N_NODES + 3) / 4;              // 25000 (1 wave/node)
    const int NB_EDGE = (N_EDGES + 255) / 256;          // 6250
    const int NB_GEMM = (N_NODES + 63) / 64;            // 1563

    zero_kernel<<<NB_NODE, 256, 0, stream>>>(cnt, N_NODES);
    detect_kernel<<<1, 256, 0, stream>>>(E, eflag);
    wa_kernel<<<1, 256, 0, stream>>>(W, KA, wa);
    transpose_kernel<<<64, 256, 0, stream>>>(W, WT);
    gemm_kernel<<<NB_GEMM, 256, 0, stream>>>(X, WT, H, N_NODES);
    score_kernel<<<NB_WAVE, 256, 0, stream>>>(X, wa, st, ssb, N_NODES);
    count_kernel<<<NB_EDGE, 256, 0, stream>>>(E, eflag, cnt, rank, N_EDGES);
    scan1_kernel<<<NB_NODE, 256, 0, stream>>>(cnt, rowp, bsum, N_NODES);
    scan2_kernel<<<1, 512, 0, stream>>>(bsum, rowp, NB_NODE, N_NODES);
    scan3_kernel<<<NB_NODE, 256, 0, stream>>>(rowp, bsum, N_NODES);
    fill_kernel<<<NB_EDGE, 256, 0, stream>>>(E, eflag, rowp, rank, csrs, N_EDGES);
    agg_kernel<<<NB_WAVE, 256, 0, stream>>>(rowp, csrs, st, ssb, H, out, N_NODES);
}

// Round 13
// 273.192 us; speedup vs baseline: 2.8965x; 1.1060x over previous
//
#include <hip/hip_runtime.h>
#include <stdint.h>

typedef unsigned short ushort_t;
typedef __attribute__((ext_vector_type(8))) short short8;   // 8 bf16 = 4 VGPRs
typedef __attribute__((ext_vector_type(4))) float float4v;  // MFMA acc

#define N_NODES 100000
#define N_EDGES 1600000
#define D 128
#define NB_GEMM 1563   // (N_NODES+63)/64
#define NB_EDGE 6250   // (N_EDGES+255)/256

static __device__ __forceinline__ float bf2f(uint32_t u) {
    return __builtin_bit_cast(float, u << 16);
}
static __device__ __forceinline__ ushort_t f2bf(float f) {
    uint32_t u = __builtin_bit_cast(uint32_t, f);
    uint32_t r = u + 0x7fffu + ((u >> 16) & 1u);   // RNE
    return (ushort_t)(r >> 16);
}
// leaky_relu(0.2) -> clip(-2,2) -> exp
static __device__ __forceinline__ float edge_e(float s) {
    float x = (s >= 0.0f) ? s : 0.2f * s;
    x = fminf(fmaxf(x, -2.0f), 2.0f);
    return __expf(x);
}

// ---------------- prep: zero cnt | transpose W->WT | detect | wa -------------
// grid 391 x 256.  All blocks zero cnt; blocks 0-63 also transpose (16384
// elems); block 64 detects edge dtype; block 65 computes wa = W @ ka.
__global__ void __launch_bounds__(256) prep_kernel(int* __restrict__ cnt, int n,
                                                   const float* __restrict__ W,
                                                   const float* __restrict__ KA,
                                                   float* __restrict__ wa,
                                                   ushort_t* __restrict__ WT,
                                                   const int* __restrict__ E,
                                                   int* __restrict__ eflag) {
    __shared__ int s;
    int b = blockIdx.x, t = threadIdx.x;
    int i = b * 256 + t;
    if (i < n) cnt[i] = 0;
    if (b < 64) {                                   // transpose + bf16 convert
        int r = i >> 7, c = i & 127;                // r = k, c = n
        WT[c * 128 + r] = f2bf(W[i]);
    } else if (b == 64) {                           // edge dtype detect
        if (t == 0) s = 0;
        __syncthreads();
        int nz = 0;
#pragma unroll
        for (int j = 0; j < 8; j++)
            if (E[(t + j * 256) * 2 + 1] != 0) nz = 1;
        if (nz) atomicOr(&s, 1);
        __syncthreads();
        if (t == 0) *eflag = (s == 0) ? 1 : 0;
    } else if (b == 65) {                           // wa = W @ ka (fp32 exact)
        int half = t >> 7, k = t & 127;
        const float* kav = KA + half * 128;
        const float* wrow = W + k * 128;
        float acc = 0.0f;
#pragma unroll 8
        for (int j = 0; j < 128; j++) acc += wrow[j] * kav[j];
        wa[half * 128 + k] = acc;
    }
}

// ---------------- mega1: [blocks 0..1562] MFMA gemm + fused score ------------
//                  [blocks 1563..7812] count (rank = atomic return) -----------
__global__ void __launch_bounds__(256) mega1_kernel(const float* __restrict__ X,
                                                    const ushort_t* __restrict__ WT,
                                                    const float* __restrict__ wa,
                                                    ushort_t* __restrict__ H,
                                                    float* __restrict__ st,
                                                    float* __restrict__ ss,
                                                    int M,
                                                    const int* __restrict__ E,
                                                    const int* __restrict__ eflag,
                                                    int* __restrict__ cnt,
                                                    int* __restrict__ rank, int ne) {
    __shared__ ushort_t lds_wt[128 * 136];    // rows padded +8: 2-way aliasing
    if (blockIdx.x >= NB_GEMM) {
        // ---------------- count branch ----------------
        int i = (blockIdx.x - NB_GEMM) * 256 + threadIdx.x;
        if (i >= ne) return;
        int i64 = *eflag;                     // wave-uniform
        int tgt = i64 ? E[i * 4] : E[i * 2];
        if ((unsigned)tgt >= (unsigned)N_NODES) tgt = 0;
        rank[i] = atomicAdd(&cnt[tgt], 1);
        return;
    }
    // ---------------- gemm + score branch ----------------
    int tid = threadIdx.x;
    for (int j = 0; j < 8; j++) {
        int chunk = tid + j * 256;            // 2048 chunks of 8 bf16
        int row = chunk >> 4, col8 = chunk & 15;
        short8 v = *(const short8*)(WT + chunk * 8);
        *(short8*)(&lds_wt[row * 136 + col8 * 8]) = v;
    }
    __syncthreads();

    int wave = tid >> 6, lane = tid & 63;
    int quad = lane >> 4, l16 = lane & 15;
    int m0 = blockIdx.x * 64 + wave * 16;

    int arow = m0 + l16; if (arow >= M) arow = M - 1;   // clamp; stores guarded
    const float* xrow = X + (size_t)arow * D + quad * 8;
    short8 a[4];
    float sct = 0.0f, scs = 0.0f;             // fp32 score partials (exact path)
#pragma unroll
    for (int kb = 0; kb < 4; kb++) {          // A[m=l16][k=kb*32+quad*8+j]
        float4 f0 = *(const float4*)(xrow + kb * 32);
        float4 f1 = *(const float4*)(xrow + kb * 32 + 4);
        const float* wt0 = wa + kb * 32 + quad * 8;
        float4 t0 = *(const float4*)(wt0);
        float4 t1 = *(const float4*)(wt0 + 4);
        float4 s0 = *(const float4*)(wt0 + 128);
        float4 s1 = *(const float4*)(wt0 + 132);
        sct += f0.x * t0.x + f0.y * t0.y + f0.z * t0.z + f0.w * t0.w
             + f1.x * t1.x + f1.y * t1.y + f1.z * t1.z + f1.w * t1.w;
        scs += f0.x * s0.x + f0.y * s0.y + f0.z * s0.z + f0.w * s0.w
             + f1.x * s1.x + f1.y * s1.y + f1.z * s1.z + f1.w * s1.w;
        short8 v;
        v[0] = (short)f2bf(f0.x); v[1] = (short)f2bf(f0.y);
        v[2] = (short)f2bf(f0.z); v[3] = (short)f2bf(f0.w);
        v[4] = (short)f2bf(f1.x); v[5] = (short)f2bf(f1.y);
        v[6] = (short)f2bf(f1.z); v[7] = (short)f2bf(f1.w);
        a[kb] = v;
    }
    // reduce score over quads (lanes l16, l16+16, l16+32, l16+48)
    sct += __shfl_xor(sct, 16); sct += __shfl_xor(sct, 32);
    scs += __shfl_xor(scs, 16); scs += __shfl_xor(scs, 32);
    if (quad == 0 && m0 + l16 < M) { st[m0 + l16] = sct; ss[m0 + l16] = scs; }

    float4v acc[8] = {};
#pragma unroll
    for (int kb = 0; kb < 4; kb++) {
#pragma unroll
        for (int t = 0; t < 8; t++) {         // B[k=kb*32+quad*8+j][n=t*16+l16]
            short8 b = *(const short8*)(&lds_wt[(t * 16 + l16) * 136 + kb * 32 + quad * 8]);
            acc[t] = __builtin_amdgcn_mfma_f32_16x16x32_bf16(a[kb], b, acc[t], 0, 0, 0);
        }
    }
    // C/D: col = lane&15, row = quad*4 + reg   [m89-verified]
#pragma unroll
    for (int t = 0; t < 8; t++) {
#pragma unroll
        for (int r = 0; r < 4; r++) {
            int orow = m0 + quad * 4 + r;
            if (orow < M) H[(size_t)orow * D + t * 16 + l16] = f2bf(acc[t][r]);
        }
    }
}

// ---------------- scan pass 1: block-local exclusive (writes i<=n) -----------
__global__ void __launch_bounds__(256) scan1_kernel(const int* __restrict__ cnt,
                                                    int* __restrict__ rowp,
                                                    int* __restrict__ bsum, int n) {
    __shared__ int lds[256];
    int t = threadIdx.x;
    int i = blockIdx.x * 256 + t;
    int v = (i < n) ? cnt[i] : 0;
    lds[t] = v;
    __syncthreads();
    for (int off = 1; off < 256; off <<= 1) {        // Hillis-Steele inclusive
        int x = (t >= off) ? lds[t - off] : 0;
        __syncthreads();
        lds[t] += x;
        __syncthreads();
    }
    if (i <= n) rowp[i] = lds[t] - v;                // partial exclusive
    if (t == 255) bsum[blockIdx.x] = lds[255];       // block total
}

// ---------------- scan pass 2: exclusive-scan the 391 block sums -------------
__global__ void __launch_bounds__(512) scan2_kernel(int* __restrict__ bsum, int nb) {
    __shared__ int lds[512];
    int t = threadIdx.x;
    int v = (t < nb) ? bsum[t] : 0;
    lds[t] = v;
    __syncthreads();
    for (int off = 1; off < 512; off <<= 1) {
        int x = (t >= off) ? lds[t - off] : 0;
        __syncthreads();
        lds[t] += x;
        __syncthreads();
    }
    if (t < nb) bsum[t] = lds[t] - v;                // exclusive block offset
}

// ---------------- fill CSR: atomic-free; final offset = rowp+bsum ------------
__global__ void fill_kernel(const int* __restrict__ E, const int* __restrict__ eflag,
                            const int* __restrict__ rowp, const int* __restrict__ bsum,
                            const int* __restrict__ rank,
                            int* __restrict__ csr_src, int ne) {
    int i = blockIdx.x * blockDim.x + threadIdx.x;
    if (i >= ne) return;
    int i64 = *eflag;                          // wave-uniform
    int tgt, src;
    if (i64) { tgt = E[i * 4]; src = E[i * 4 + 2]; }
    else     { tgt = E[i * 2]; src = E[i * 2 + 1]; }
    if ((unsigned)tgt >= (unsigned)N_NODES) tgt = 0;
    if ((unsigned)src >= (unsigned)N_NODES) src = 0;
    csr_src[rowp[tgt] + bsum[tgt >> 8] + rank[i]] = src;
}

// ---------------- aggregation: 4 edges in flight per wave --------------------
__global__ void __launch_bounds__(256) agg_kernel(const int* __restrict__ rowp,
                                                  const int* __restrict__ bsum,
                                                  const int* __restrict__ csr_src,
                                                  const float* __restrict__ st,
                                                  const float* __restrict__ ss,
                                                  const ushort_t* __restrict__ H,
                                                  float* __restrict__ out, int n) {
    int wave = threadIdx.x >> 6, lane = threadIdx.x & 63;
    int node = blockIdx.x * 4 + wave;
    if (node >= n) return;
    node = __builtin_amdgcn_readfirstlane(node);  // scalarize rowp/st loads
    int g = lane >> 4, l = lane & 15;
    int start = rowp[node] + bsum[node >> 8];
    int end   = rowp[node + 1] + bsum[(node + 1) >> 8];
    float stn = st[node];
    float den = 0.0f;
    float acc[8] = {};
    for (int m = start + g; m < end; m += 4) {
        int src = csr_src[m];                     // group-uniform
        float e = edge_e(stn + ss[src]);
        den += e;
        uint4 p = *(const uint4*)(H + (size_t)src * D + l * 8);  // 8 bf16
        acc[0] += e * bf2f(p.x & 0xffff); acc[1] += e * bf2f(p.x >> 16);
        acc[2] += e * bf2f(p.y & 0xffff); acc[3] += e * bf2f(p.y >> 16);
        acc[4] += e * bf2f(p.z & 0xffff); acc[5] += e * bf2f(p.z >> 16);
        acc[6] += e * bf2f(p.w & 0xffff); acc[7] += e * bf2f(p.w >> 16);
    }
    den += __shfl_xor(den, 16);
    den += __shfl_xor(den, 32);
#pragma unroll
    for (int j = 0; j < 8; j++) {
        acc[j] += __shfl_xor(acc[j], 16);
        acc[j] += __shfl_xor(acc[j], 32);
    }
    float inv = 1.0f / (den + 1e-9f);
    if (g == 0) {                                 // 16 lanes store 512B row
        float4 o0 = make_float4(acc[0] * inv, acc[1] * inv, acc[2] * inv, acc[3] * inv);
        float4 o1 = make_float4(acc[4] * inv, acc[5] * inv, acc[6] * inv, acc[7] * inv);
        *(float4*)(out + (size_t)node * D + l * 8) = o0;
        *(float4*)(out + (size_t)node * D + l * 8 + 4) = o1;
    }
}

extern "C" void kernel_launch(void* const* d_in, const int* in_sizes, int n_in,
                              void* d_out, int out_size, void* d_ws, size_t ws_size,
                              hipStream_t stream) {
    const float* X  = (const float*)d_in[0];
    const int*   E  = (const int*)d_in[1];
    const float* W  = (const float*)d_in[2];
    const float* KA = (const float*)d_in[3];
    for (int i = 0; i < n_in; i++) {
        int s = in_sizes[i];
        if (s == N_NODES * D)      X  = (const float*)d_in[i];
        else if (s == N_EDGES * 2) E  = (const int*)d_in[i];
        else if (s == D * D)       W  = (const float*)d_in[i];
        else if (s == 2 * D)       KA = (const float*)d_in[i];
    }
    float* out = (float*)d_out;                // fp32 [100000,128]
    int* rank = (int*)d_out;                   // 6.4 MB scratch in d_out head

    char* ws = (char*)d_ws;
    // workspace layout (16B aligned), total ~33.6 MB
    ushort_t* H        = (ushort_t*)(ws + 0);           // 25,600,000 B (bf16 h)
    float*    wa       = (float*)   (ws + 25600000);    //      1,024 B
    float*    st       = (float*)   (ws + 25601024);    //    400,000 B
    float*    ssb      = (float*)   (ws + 26001024);    //    400,000 B
    int*      cnt      = (int*)     (ws + 26401024);    //    400,000 B
    int*      rowp     = (int*)     (ws + 26801024);    //    400,016 B
    int*      csrs     = (int*)     (ws + 27201040);    //  6,400,000 B
    int*      eflag    = (int*)     (ws + 33601040);    //         16 B
    int*      bsum     = (int*)     (ws + 33601056);    //      1,600 B
    ushort_t* WT       = (ushort_t*)(ws + 33602656);    //     32,768 B

    const int NB_NODE = (N_NODES + 255) / 256;          // 391
    const int NB_WAVE = (N_NODES + 3) / 4;              // 25000 (1 wave/node)

    prep_kernel<<<NB_NODE, 256, 0, stream>>>(cnt, N_NODES, W, KA, wa, WT, E, eflag);
    mega1_kernel<<<NB_GEMM + NB_EDGE, 256, 0, stream>>>(X, WT, wa, H, st, ssb,
                                                        N_NODES, E, eflag, cnt,
                                                        rank, N_EDGES);
    scan1_kernel<<<NB_NODE, 256, 0, stream>>>(cnt, rowp, bsum, N_NODES);
    scan2_kernel<<<1, 512, 0, stream>>>(bsum, NB_NODE);
    fill_kernel<<<NB_EDGE, 256, 0, stream>>>(E, eflag, rowp, bsum, rank, csrs, N_EDGES);
    agg_kernel<<<NB_WAVE, 256, 0, stream>>>(rowp, bsum, csrs, st, ssb, H, out, N_NODES);
}